// Round 16
// baseline (142.635 us; speedup 1.0000x reference)
//
#include <hip/hip_runtime.h>

#define BS    131072
#define HID   256
#define ROWS  64          // rows per block (= lanes per wave)
#define NW    4           // waves per block = hidden slices
#define SLICE (HID / NW)  // 64 hidden units per wave

// tanh(x) = 1 - 2/(exp(2x)+1); exp via v_exp_f32, rcp via v_rcp_f32.
// Saturates correctly at +-inf. ~1e-6 abs err (threshold is 0.22).
__device__ __forceinline__ float fast_tanh(float x) {
    float e = __expf(2.0f * x);
    return 1.0f - 2.0f * __builtin_amdgcn_rcpf(e + 1.0f);
}

// (256,4): 4 waves/EU min -> VGPR cap 128, room for the 64-reg q-cache.
// (256,8) would force <=64 VGPR and spill the cache to scratch.
__global__ __launch_bounds__(256, 4) void hnn_kernel(
    const float* __restrict__ y,
    const float* __restrict__ MW1, const float* __restrict__ Mb1,
    const float* __restrict__ MW2, const float* __restrict__ Mb2,
    const float* __restrict__ HW1, const float* __restrict__ Hb1,
    const float* __restrict__ HW2,
    const float* __restrict__ gW1, const float* __restrict__ gb1,
    const float* __restrict__ gW2, const float* __restrict__ gb2,
    float* __restrict__ out)
{
    // partial-sum exchange: [value][wave][lane], lane stride 1 -> conflict-free
    __shared__ float red[15][NW][ROWS];

    const int tid = threadIdx.x;
    // readfirstlane: force wave-uniformity so weight loads stay s_load
    const int w   = __builtin_amdgcn_readfirstlane(tid >> 6);
    const int l   = tid & 63;
    const int row = blockIdx.x * ROWS + l;
    const int h0  = w * SLICE;

    const float* yb = y + row * 6;
    const float x0  = yb[0];   // x
    const float x1  = yb[1];   // cos_q
    const float x2  = yb[2];   // sin_q
    const float xd0 = yb[3];
    const float xd1 = yb[4];
    const float u   = yb[5];

    // q-cache: 1 - tanh(pre_M)^2 for this wave's 64 hidden units.
    // Fully-unrolled loops keep indexing static -> registers, not scratch.
    float thq[SLICE];

    // ---------- Pass A partials: M-net fwd + g-net over this wave's slice ----------
    float a0=0.f, a1=0.f, a2=0.f, a3=0.f, g0=0.f, g1=0.f;
    #pragma unroll
    for (int i = 0; i < SLICE; ++i) {
        const int h = h0 + i;
        float pre = fmaf(x0, MW1[h],
                    fmaf(x1, MW1[HID + h],
                    fmaf(x2, MW1[2 * HID + h], Mb1[h])));
        float th = fast_tanh(pre);
        thq[i] = fmaf(-th, th, 1.0f);          // cache 1-th^2 for the JVP pass
        a0 = fmaf(th, MW2[4 * h + 0], a0);
        a1 = fmaf(th, MW2[4 * h + 1], a1);
        a2 = fmaf(th, MW2[4 * h + 2], a2);
        a3 = fmaf(th, MW2[4 * h + 3], a3);

        float gp = fmaf(x0, gW1[h],
                   fmaf(x1, gW1[HID + h],
                   fmaf(x2, gW1[2 * HID + h], gb1[h])));
        float gt = fast_tanh(gp);
        g0 = fmaf(gt, gW2[2 * h + 0], g0);
        g1 = fmaf(gt, gW2[2 * h + 1], g1);
    }
    red[0][w][l] = a0;  red[1][w][l] = a1;  red[2][w][l] = a2;  red[3][w][l] = a3;
    red[4][w][l] = g0;  red[5][w][l] = g1;
    __syncthreads();
    // combine (every thread; bitwise-identical across the 4 redundant copies)
    a0 = ((red[0][0][l] + red[0][1][l]) + (red[0][2][l] + red[0][3][l])) + Mb2[0];
    a1 = ((red[1][0][l] + red[1][1][l]) + (red[1][2][l] + red[1][3][l])) + Mb2[1];
    a2 = ((red[2][0][l] + red[2][1][l]) + (red[2][2][l] + red[2][3][l])) + Mb2[2];
    a3 = ((red[3][0][l] + red[3][1][l]) + (red[3][2][l] + red[3][3][l])) + Mb2[3];
    g0 = ((red[4][0][l] + red[4][1][l]) + (red[4][2][l] + red[4][3][l])) + gb2[0];
    g1 = ((red[5][0][l] + red[5][1][l]) + (red[5][2][l] + red[5][3][l])) + gb2[1];

    // M_inv = a a^T + I (a = [[a0,a1],[a2,a3]]), symmetric; det >= 1
    const float M00 = fmaf(a0, a0, a1 * a1) + 1.0f;
    const float M01 = fmaf(a0, a2, a1 * a3);
    const float M11 = fmaf(a2, a2, a3 * a3) + 1.0f;
    const float det  = fmaf(M00, M11, -(M01 * M01));
    const float rdet = __builtin_amdgcn_rcpf(det);
    const float p0 = (M11 * xd0 - M01 * xd1) * rdet;
    const float p1 = (M00 * xd1 - M01 * xd0) * rdet;

    // ---------- Pass B partials: dH = grad H-net at (x0,x1,x2,p0,p1) ----------
    float dH0=0.f, dH1=0.f, dH2=0.f, dH3=0.f, dH4=0.f;
    #pragma unroll 4
    for (int i = 0; i < SLICE; ++i) {
        const int h = h0 + i;
        float w0 = HW1[h];
        float w1 = HW1[HID + h];
        float w2 = HW1[2 * HID + h];
        float w3 = HW1[3 * HID + h];
        float w4 = HW1[4 * HID + h];
        float pre = fmaf(x0, w0,
                    fmaf(x1, w1,
                    fmaf(x2, w2,
                    fmaf(p0, w3,
                    fmaf(p1, w4, Hb1[h])))));
        float th = fast_tanh(pre);
        float s  = fmaf(-th, th, 1.0f) * HW2[h];
        dH0 = fmaf(w0, s, dH0);
        dH1 = fmaf(w1, s, dH1);
        dH2 = fmaf(w2, s, dH2);
        dH3 = fmaf(w3, s, dH3);
        dH4 = fmaf(w4, s, dH4);
    }
    red[6][w][l] = dH0;  red[7][w][l] = dH1;  red[8][w][l] = dH2;
    red[9][w][l] = dH3;  red[10][w][l] = dH4;
    __syncthreads();
    dH0 = (red[6][0][l]  + red[6][1][l])  + (red[6][2][l]  + red[6][3][l]);
    dH1 = (red[7][0][l]  + red[7][1][l])  + (red[7][2][l]  + red[7][3][l]);
    dH2 = (red[8][0][l]  + red[8][1][l])  + (red[8][2][l]  + red[8][3][l]);
    dH3 = (red[9][0][l]  + red[9][1][l])  + (red[9][2][l]  + red[9][3][l]);
    dH4 = (red[10][0][l] + red[10][1][l]) + (red[10][2][l] + red[10][3][l]);

    const float F0 = g0 * u, F1 = g1 * u;
    const float dx = dH3, dq = dH4;
    const float dp0 = F0 - dH0;
    const float dp1 = fmaf(x2, dH1, -(x1 * dH2)) + F1;  // sin*dHdcos - cos*dHdsin + F1
    const float v0 = dx;
    const float v1 = -(x2 * dq);
    const float v2 = x1 * dq;

    // ---------- Pass C partials: JVP of M-net along v (tanh from q-cache) ----------
    float da0=0.f, da1=0.f, da2=0.f, da3=0.f;
    #pragma unroll
    for (int i = 0; i < SLICE; ++i) {
        const int h = h0 + i;
        float w0 = MW1[h];
        float w1 = MW1[HID + h];
        float w2 = MW1[2 * HID + h];
        float dpre = fmaf(v0, w0, fmaf(v1, w1, v2 * w2));
        float dt   = thq[i] * dpre;            // (1-th^2)*dpre, no recompute
        da0 = fmaf(dt, MW2[4 * h + 0], da0);
        da1 = fmaf(dt, MW2[4 * h + 1], da1);
        da2 = fmaf(dt, MW2[4 * h + 2], da2);
        da3 = fmaf(dt, MW2[4 * h + 3], da3);
    }
    red[11][w][l] = da0;  red[12][w][l] = da1;
    red[13][w][l] = da2;  red[14][w][l] = da3;
    __syncthreads();
    if (w == 0) {
        da0 = (red[11][0][l] + red[11][1][l]) + (red[11][2][l] + red[11][3][l]);
        da1 = (red[12][0][l] + red[12][1][l]) + (red[12][2][l] + red[12][3][l]);
        da2 = (red[13][0][l] + red[13][1][l]) + (red[13][2][l] + red[13][3][l]);
        da3 = (red[14][0][l] + red[14][1][l]) + (red[14][2][l] + red[14][3][l]);

        // dM = da a^T + a da^T (symmetric)
        const float dM00 = 2.0f * fmaf(da0, a0, da1 * a1);
        const float dM01 = fmaf(da0, a2, fmaf(da1, a3, fmaf(a0, da2, a1 * da3)));
        const float dM11 = 2.0f * fmaf(da2, a2, da3 * a3);

        // ddq = M_inv @ dp + dM @ p
        const float ddq0 = fmaf(M00, dp0, fmaf(M01, dp1, fmaf(dM00, p0, dM01 * p1)));
        const float ddq1 = fmaf(M01, dp0, fmaf(M11, dp1, fmaf(dM01, p0, dM11 * p1)));

        float* ob = out + row * 6;
        ob[0] = dx;
        ob[1] = v1;
        ob[2] = v2;
        ob[3] = ddq0;
        ob[4] = ddq1;
        ob[5] = 0.0f;
    }
}

extern "C" void kernel_launch(void* const* d_in, const int* in_sizes, int n_in,
                              void* d_out, int out_size, void* d_ws, size_t ws_size,
                              hipStream_t stream) {
    // setup_inputs order:
    // 0:t 1:y 2:M_W1 3:M_b1 4:M_W2 5:M_b2 6:H_W1 7:H_b1 8:H_W2 9:H_b2
    // 10:g_W1 11:g_b1 12:g_W2 13:g_b2
    const float* y   = (const float*)d_in[1];
    const float* MW1 = (const float*)d_in[2];
    const float* Mb1 = (const float*)d_in[3];
    const float* MW2 = (const float*)d_in[4];
    const float* Mb2 = (const float*)d_in[5];
    const float* HW1 = (const float*)d_in[6];
    const float* Hb1 = (const float*)d_in[7];
    const float* HW2 = (const float*)d_in[8];
    const float* gW1 = (const float*)d_in[10];
    const float* gb1 = (const float*)d_in[11];
    const float* gW2 = (const float*)d_in[12];
    const float* gb2 = (const float*)d_in[13];
    float* out = (float*)d_out;

    hnn_kernel<<<BS / ROWS, NW * 64, 0, stream>>>(
        y, MW1, Mb1, MW2, Mb2, HW1, Hb1, HW2, gW1, gb1, gW2, gb2, out);
}

// Round 17
// 132.921 us; speedup vs baseline: 1.0731x; 1.0731x over previous
//
#include <hip/hip_runtime.h>

#define BS    131072
#define HID   256
#define ROWS  64          // rows per block (= lanes per wave)
#define NW    4           // waves per block = hidden slices
#define SLICE (HID / NW)  // 64 hidden units per wave
#define NRED  18          // reduction slots: a0-3, g0-1, J[3][4]

// tanh(x) = 1 - 2/(exp(2x)+1); exp via v_exp_f32, rcp via v_rcp_f32.
// Saturates correctly at +-inf. ~1e-6 abs err (threshold is 0.22).
__device__ __forceinline__ float fast_tanh(float x) {
    float e = __expf(2.0f * x);
    return 1.0f - 2.0f * __builtin_amdgcn_rcpf(e + 1.0f);
}

__global__ __launch_bounds__(256, 8) void hnn_kernel(
    const float* __restrict__ y,
    const float* __restrict__ MW1, const float* __restrict__ Mb1,
    const float* __restrict__ MW2, const float* __restrict__ Mb2,
    const float* __restrict__ HW1, const float* __restrict__ Hb1,
    const float* __restrict__ HW2,
    const float* __restrict__ gW1, const float* __restrict__ gb1,
    const float* __restrict__ gW2, const float* __restrict__ gb2,
    float* __restrict__ out)
{
    // partial-sum exchange: [value][wave][lane], lane stride 1 -> conflict-free.
    // Round 1: slots 0-17 (a, g, J). Round 2: slots 0-4 reused for dH.
    __shared__ float red[NRED][NW][ROWS];

    const int tid = threadIdx.x;
    // readfirstlane: force wave-uniformity so weight loads stay s_load
    const int w   = __builtin_amdgcn_readfirstlane(tid >> 6);
    const int l   = tid & 63;
    const int row = blockIdx.x * ROWS + l;
    const int h0  = w * SLICE;

    const float* yb = y + row * 6;
    const float x0  = yb[0];   // x
    const float x1  = yb[1];   // cos_q
    const float x2  = yb[2];   // sin_q
    const float xd0 = yb[3];
    const float xd1 = yb[4];
    const float u   = yb[5];

    // ---------- Pass A: M-net fwd + g-net + JVP-Jacobian contraction ----------
    // J[k][j] = sum_h (1-th^2) * MW1[k,h] * MW2[h,j]  (JVP is linear in v:
    // da_j = v0*J0j + v1*J1j + v2*J2j) -- eliminates the old Pass C entirely.
    float a0=0.f, a1=0.f, a2=0.f, a3=0.f, g0=0.f, g1=0.f;
    float J00=0.f,J01=0.f,J02=0.f,J03=0.f;
    float J10=0.f,J11=0.f,J12=0.f,J13=0.f;
    float J20=0.f,J21=0.f,J22=0.f,J23=0.f;
    #pragma unroll 4
    for (int i = 0; i < SLICE; ++i) {
        const int h = h0 + i;
        float w0 = MW1[h];
        float w1 = MW1[HID + h];
        float w2 = MW1[2 * HID + h];
        float pre = fmaf(x0, w0, fmaf(x1, w1, fmaf(x2, w2, Mb1[h])));
        float th  = fast_tanh(pre);
        float q   = fmaf(-th, th, 1.0f);
        float m0 = MW2[4 * h + 0];
        float m1 = MW2[4 * h + 1];
        float m2 = MW2[4 * h + 2];
        float m3 = MW2[4 * h + 3];
        a0 = fmaf(th, m0, a0);
        a1 = fmaf(th, m1, a1);
        a2 = fmaf(th, m2, a2);
        a3 = fmaf(th, m3, a3);
        float qw0 = q * w0, qw1 = q * w1, qw2 = q * w2;
        J00 = fmaf(qw0, m0, J00);  J01 = fmaf(qw0, m1, J01);
        J02 = fmaf(qw0, m2, J02);  J03 = fmaf(qw0, m3, J03);
        J10 = fmaf(qw1, m0, J10);  J11 = fmaf(qw1, m1, J11);
        J12 = fmaf(qw1, m2, J12);  J13 = fmaf(qw1, m3, J13);
        J20 = fmaf(qw2, m0, J20);  J21 = fmaf(qw2, m1, J21);
        J22 = fmaf(qw2, m2, J22);  J23 = fmaf(qw2, m3, J23);

        float gp = fmaf(x0, gW1[h],
                   fmaf(x1, gW1[HID + h],
                   fmaf(x2, gW1[2 * HID + h], gb1[h])));
        float gt = fast_tanh(gp);
        g0 = fmaf(gt, gW2[2 * h + 0], g0);
        g1 = fmaf(gt, gW2[2 * h + 1], g1);
    }
    red[0][w][l] = a0;   red[1][w][l] = a1;   red[2][w][l] = a2;   red[3][w][l] = a3;
    red[4][w][l] = g0;   red[5][w][l] = g1;
    red[6][w][l]  = J00; red[7][w][l]  = J01; red[8][w][l]  = J02; red[9][w][l]  = J03;
    red[10][w][l] = J10; red[11][w][l] = J11; red[12][w][l] = J12; red[13][w][l] = J13;
    red[14][w][l] = J20; red[15][w][l] = J21; red[16][w][l] = J22; red[17][w][l] = J23;
    __syncthreads();
    // every thread needs a (for p / Pass B); g only needed by wave 0 but slot 4
    // is overwritten by dH below, so combine it now (cheap).
    a0 = ((red[0][0][l] + red[0][1][l]) + (red[0][2][l] + red[0][3][l])) + Mb2[0];
    a1 = ((red[1][0][l] + red[1][1][l]) + (red[1][2][l] + red[1][3][l])) + Mb2[1];
    a2 = ((red[2][0][l] + red[2][1][l]) + (red[2][2][l] + red[2][3][l])) + Mb2[2];
    a3 = ((red[3][0][l] + red[3][1][l]) + (red[3][2][l] + red[3][3][l])) + Mb2[3];
    g0 = ((red[4][0][l] + red[4][1][l]) + (red[4][2][l] + red[4][3][l])) + gb2[0];
    g1 = ((red[5][0][l] + red[5][1][l]) + (red[5][2][l] + red[5][3][l])) + gb2[1];

    // M_inv = a a^T + I (a = [[a0,a1],[a2,a3]]), symmetric; det >= 1
    const float M00 = fmaf(a0, a0, a1 * a1) + 1.0f;
    const float M01 = fmaf(a0, a2, a1 * a3);
    const float M11 = fmaf(a2, a2, a3 * a3) + 1.0f;
    const float det  = fmaf(M00, M11, -(M01 * M01));
    const float rdet = __builtin_amdgcn_rcpf(det);
    const float p0 = (M11 * xd0 - M01 * xd1) * rdet;
    const float p1 = (M00 * xd1 - M01 * xd0) * rdet;

    // ---------- Pass B: dH = grad H-net at (x0,x1,x2,p0,p1) ----------
    float dH0=0.f, dH1=0.f, dH2=0.f, dH3=0.f, dH4=0.f;
    #pragma unroll 4
    for (int i = 0; i < SLICE; ++i) {
        const int h = h0 + i;
        float w0 = HW1[h];
        float w1 = HW1[HID + h];
        float w2 = HW1[2 * HID + h];
        float w3 = HW1[3 * HID + h];
        float w4 = HW1[4 * HID + h];
        float pre = fmaf(x0, w0,
                    fmaf(x1, w1,
                    fmaf(x2, w2,
                    fmaf(p0, w3,
                    fmaf(p1, w4, Hb1[h])))));
        float th = fast_tanh(pre);
        float s  = fmaf(-th, th, 1.0f) * HW2[h];
        dH0 = fmaf(w0, s, dH0);
        dH1 = fmaf(w1, s, dH1);
        dH2 = fmaf(w2, s, dH2);
        dH3 = fmaf(w3, s, dH3);
        dH4 = fmaf(w4, s, dH4);
    }
    red[0][w][l] = dH0;  red[1][w][l] = dH1;  red[2][w][l] = dH2;
    red[3][w][l] = dH3;  red[4][w][l] = dH4;
    __syncthreads();

    // Only wave 0 finishes: dH combine, J combine (slots 6-17 still intact),
    // 2x2 algebra, output.
    if (w == 0) {
        dH0 = (red[0][0][l] + red[0][1][l]) + (red[0][2][l] + red[0][3][l]);
        dH1 = (red[1][0][l] + red[1][1][l]) + (red[1][2][l] + red[1][3][l]);
        dH2 = (red[2][0][l] + red[2][1][l]) + (red[2][2][l] + red[2][3][l]);
        dH3 = (red[3][0][l] + red[3][1][l]) + (red[3][2][l] + red[3][3][l]);
        dH4 = (red[4][0][l] + red[4][1][l]) + (red[4][2][l] + red[4][3][l]);

        J00 = (red[6][0][l]  + red[6][1][l])  + (red[6][2][l]  + red[6][3][l]);
        J01 = (red[7][0][l]  + red[7][1][l])  + (red[7][2][l]  + red[7][3][l]);
        J02 = (red[8][0][l]  + red[8][1][l])  + (red[8][2][l]  + red[8][3][l]);
        J03 = (red[9][0][l]  + red[9][1][l])  + (red[9][2][l]  + red[9][3][l]);
        J10 = (red[10][0][l] + red[10][1][l]) + (red[10][2][l] + red[10][3][l]);
        J11 = (red[11][0][l] + red[11][1][l]) + (red[11][2][l] + red[11][3][l]);
        J12 = (red[12][0][l] + red[12][1][l]) + (red[12][2][l] + red[12][3][l]);
        J13 = (red[13][0][l] + red[13][1][l]) + (red[13][2][l] + red[13][3][l]);
        J20 = (red[14][0][l] + red[14][1][l]) + (red[14][2][l] + red[14][3][l]);
        J21 = (red[15][0][l] + red[15][1][l]) + (red[15][2][l] + red[15][3][l]);
        J22 = (red[16][0][l] + red[16][1][l]) + (red[16][2][l] + red[16][3][l]);
        J23 = (red[17][0][l] + red[17][1][l]) + (red[17][2][l] + red[17][3][l]);

        const float F0 = g0 * u, F1 = g1 * u;
        const float dx = dH3, dq = dH4;
        const float dp0 = F0 - dH0;
        const float dp1 = fmaf(x2, dH1, -(x1 * dH2)) + F1; // sin*dHdcos - cos*dHdsin + F1
        const float v0 = dx;
        const float v1 = -(x2 * dq);
        const float v2 = x1 * dq;

        // da = v . J  (JVP of a along v)
        const float da0 = fmaf(v0, J00, fmaf(v1, J10, v2 * J20));
        const float da1 = fmaf(v0, J01, fmaf(v1, J11, v2 * J21));
        const float da2 = fmaf(v0, J02, fmaf(v1, J12, v2 * J22));
        const float da3 = fmaf(v0, J03, fmaf(v1, J13, v2 * J23));

        // dM = da a^T + a da^T (symmetric)
        const float dM00 = 2.0f * fmaf(da0, a0, da1 * a1);
        const float dM01 = fmaf(da0, a2, fmaf(da1, a3, fmaf(a0, da2, a1 * da3)));
        const float dM11 = 2.0f * fmaf(da2, a2, da3 * a3);

        // ddq = M_inv @ dp + dM @ p
        const float ddq0 = fmaf(M00, dp0, fmaf(M01, dp1, fmaf(dM00, p0, dM01 * p1)));
        const float ddq1 = fmaf(M01, dp0, fmaf(M11, dp1, fmaf(dM01, p0, dM11 * p1)));

        float* ob = out + row * 6;
        ob[0] = dx;
        ob[1] = v1;
        ob[2] = v2;
        ob[3] = ddq0;
        ob[4] = ddq1;
        ob[5] = 0.0f;
    }
}

extern "C" void kernel_launch(void* const* d_in, const int* in_sizes, int n_in,
                              void* d_out, int out_size, void* d_ws, size_t ws_size,
                              hipStream_t stream) {
    // setup_inputs order:
    // 0:t 1:y 2:M_W1 3:M_b1 4:M_W2 5:M_b2 6:H_W1 7:H_b1 8:H_W2 9:H_b2
    // 10:g_W1 11:g_b1 12:g_W2 13:g_b2
    const float* y   = (const float*)d_in[1];
    const float* MW1 = (const float*)d_in[2];
    const float* Mb1 = (const float*)d_in[3];
    const float* MW2 = (const float*)d_in[4];
    const float* Mb2 = (const float*)d_in[5];
    const float* HW1 = (const float*)d_in[6];
    const float* Hb1 = (const float*)d_in[7];
    const float* HW2 = (const float*)d_in[8];
    const float* gW1 = (const float*)d_in[10];
    const float* gb1 = (const float*)d_in[11];
    const float* gW2 = (const float*)d_in[12];
    const float* gb2 = (const float*)d_in[13];
    float* out = (float*)d_out;

    hnn_kernel<<<BS / ROWS, NW * 64, 0, stream>>>(
        y, MW1, Mb1, MW2, Mb2, HW1, Hb1, HW2, gW1, gb1, gW2, gb2, out);
}